// Round 1
// baseline (347.235 us; speedup 1.0000x reference)
//
#include <hip/hip_runtime.h>
#include <hip/hip_bf16.h>
#include <stdint.h>
#include <string.h>

// Problem constants (fixed by the reference)
#define NUM_CHIPS 4
#define N_EXPERTS 32
#define TOP_K 4
#define SEQ 1024
#define HIDDEN 2048
#define MAX_TOK 1024
#define META_LEN 8
#define NPC (SEQ * TOP_K)            // 4096 assignments per chip
#define ROWS (N_EXPERTS * MAX_TOK)   // 32768 output rows
#define BUF_ELEMS ((size_t)ROWS * HIDDEN)           // 67,108,864
#define META_OFF BUF_ELEMS
#define CNT_OFF (BUF_ELEMS + (size_t)ROWS * META_LEN)

// ---------------------------------------------------------------------------
// Plan kernel: single block, replicates the reference's serialized
// chip0..chip3, (token,topk)-order offset-counter loop.
// Stable rank within each 256-chunk via wave ballots + cross-wave LDS scan.
// ---------------------------------------------------------------------------
__global__ __launch_bounds__(256) void plan_kernel(const int* __restrict__ idx,
                                                   int* __restrict__ inv,
                                                   float* __restrict__ out) {
    __shared__ int run_base[N_EXPERTS];      // running slot counter per expert
    __shared__ int wave_cnt[4][N_EXPERTS];   // per-wave per-expert counts in chunk
    __shared__ int wave_base[4][N_EXPERTS];  // exclusive base for each wave

    const int t = threadIdx.x;
    const int lane = t & 63;
    const int w = t >> 6;

    if (t < N_EXPERTS) run_base[t] = 0;
    __syncthreads();

    for (int c = 0; c < NUM_CHIPS; ++c) {
        for (int chunk = 0; chunk < NPC / 256; ++chunk) {
            const int n = chunk * 256 + t;          // (token,topk) flat index
            const int e = idx[c * NPC + n];         // routed expert, 0..31

            if (t < 4 * N_EXPERTS) ((int*)wave_cnt)[t] = 0;
            __syncthreads();

            // mask of lanes in this wave routed to the same expert
            uint64_t m = ~0ull;
#pragma unroll
            for (int b = 0; b < 5; ++b) {
                uint64_t bb = __ballot((e >> b) & 1);
                m &= ((e >> b) & 1) ? bb : ~bb;
            }
            const uint64_t below = (1ull << lane) - 1ull;
            const int rk = __popcll(m & below);     // stable rank within wave
            if (rk == 0) wave_cnt[w][e] = __popcll(m);  // group leader
            __syncthreads();

            // cross-wave exclusive scan per expert + update running base
            if (t < N_EXPERTS) {
                int s = run_base[t];
#pragma unroll
                for (int ww = 0; ww < 4; ++ww) {
                    wave_base[ww][t] = s;
                    s += wave_cnt[ww][t];
                }
                run_base[t] = s;
            }
            __syncthreads();

            const int dst = wave_base[w][e] + rk;   // slot within expert buffer
            const int flat = e * MAX_TOK + dst;     // global output row
            inv[flat] = (c << 12) | n;              // inverse map for scatter
            // no extra sync needed: next iteration only touches wave_cnt before
            // its own __syncthreads(); wave_base is rewritten two syncs later.
        }
    }
    __syncthreads();
    if (t < N_EXPERTS) out[CNT_OFF + t] = (float)run_base[t];
}

// ---------------------------------------------------------------------------
// Scatter kernel: one block per output row. Copies the token's hidden vector
// (or zeros) + writes the 8-entry metadata row (or -1s).
// ---------------------------------------------------------------------------
__global__ __launch_bounds__(256) void scatter_kernel(const float* __restrict__ x,
                                                      const float* __restrict__ wts,
                                                      const int* __restrict__ inv,
                                                      float* __restrict__ out) {
    const int row = blockIdx.x;
    const int t = threadIdx.x;
    const int iv = inv[row];

    float4* dst = (float4*)(out + (size_t)row * HIDDEN);

    if (iv >= 0) {
        const int c = iv >> 12;
        const int n = iv & (NPC - 1);
        const int token = n >> 2;
        const float4* src = (const float4*)(x + ((size_t)c * SEQ + token) * HIDDEN);
#pragma unroll
        for (int i = 0; i < HIDDEN / 4 / 256; ++i)
            dst[t + i * 256] = src[t + i * 256];

        if (t < META_LEN) {
            float v = 0.0f;
            if (t == 0) v = (float)c;
            else if (t == 1) v = (float)token;
            else if (t == 2) v = (float)(n & 3);
            else if (t == 3) v = (float)(row >> 10);   // expert id
            else if (t == 4) {
                // bf16 bits of the routing weight, RNE (matches jax astype)
                float wv = wts[c * NPC + n];
                uint32_t ub;
                memcpy(&ub, &wv, 4);
                uint32_t lsb = (ub >> 16) & 1u;
                uint32_t bits = (ub + 0x7FFFu + lsb) >> 16;
                v = (float)(int)(short)(uint16_t)bits; // sign-extend int16
            }
            out[META_OFF + (size_t)row * META_LEN + t] = v;
        }
    } else {
        const float4 z = make_float4(0.f, 0.f, 0.f, 0.f);
#pragma unroll
        for (int i = 0; i < HIDDEN / 4 / 256; ++i)
            dst[t + i * 256] = z;
        if (t < META_LEN)
            out[META_OFF + (size_t)row * META_LEN + t] = -1.0f;
    }
}

extern "C" void kernel_launch(void* const* d_in, const int* in_sizes, int n_in,
                              void* d_out, int out_size, void* d_ws, size_t ws_size,
                              hipStream_t stream) {
    const float* x   = (const float*)d_in[0];   // [4,1024,2048] f32
    const float* wts = (const float*)d_in[1];   // [4,1024,4]    f32
    const int*   idx = (const int*)d_in[2];     // [4,1024,4]    i32
    float* out = (float*)d_out;
    int* inv = (int*)d_ws;                      // [32768] inverse map

    // inv = -1 everywhere (0xFF bytes). hipMemsetAsync is graph-capture safe.
    hipMemsetAsync(inv, 0xFF, (size_t)ROWS * sizeof(int), stream);

    plan_kernel<<<1, 256, 0, stream>>>(idx, inv, out);
    scatter_kernel<<<ROWS, 256, 0, stream>>>(x, wts, inv, out);
}

// Round 2
// 300.952 us; speedup vs baseline: 1.1538x; 1.1538x over previous
//
#include <hip/hip_runtime.h>
#include <hip/hip_bf16.h>
#include <stdint.h>
#include <string.h>

// Problem constants (fixed by the reference)
#define NUM_CHIPS 4
#define N_EXPERTS 32
#define TOP_K 4
#define SEQ 1024
#define HIDDEN 2048
#define MAX_TOK 1024
#define META_LEN 8
#define NPC (SEQ * TOP_K)            // 4096 assignments per chip
#define NTOT (NUM_CHIPS * NPC)       // 16384 assignments total
#define ROWS (N_EXPERTS * MAX_TOK)   // 32768 output rows
#define BUF_ELEMS ((size_t)ROWS * HIDDEN)           // 67,108,864
#define META_OFF BUF_ELEMS
#define CNT_OFF (BUF_ELEMS + (size_t)ROWS * META_LEN)

// Workspace layout (ints)
#define WS_RANK 0                    // [NTOT]  within-chip stable rank
#define WS_CNT  (NTOT)               // [4][32] per-chip per-expert counts
#define WS_TOT  (NTOT + 128)         // [32]    total per-expert counts
#define WS_INV  (NTOT + 128 + 32)    // [ROWS]  inverse map (only occupied slots written)

// ---------------------------------------------------------------------------
// rank_kernel: one block per chip, 1024 threads. All 4096 expert ids are
// loaded into registers up-front (coalesced), so the 4 serial chunk
// iterations contain only ballots + LDS — no global latency in the loop.
// Produces, per chip: stable rank of each assignment within its expert group
// (preserving (token, topk) order) and per-expert counts.
// ---------------------------------------------------------------------------
__global__ __launch_bounds__(1024) void rank_kernel(const int* __restrict__ idx,
                                                    int* __restrict__ ws) {
    __shared__ int run_base[N_EXPERTS];       // running per-expert count
    __shared__ int wave_cnt[16][N_EXPERTS];   // per-wave group sizes in chunk
    __shared__ int wave_base[16][N_EXPERTS];  // exclusive base per wave

    const int c = blockIdx.x;
    const int t = threadIdx.x;
    const int lane = t & 63;
    const int w = t >> 6;

    int e[4];
#pragma unroll
    for (int q = 0; q < 4; ++q) e[q] = idx[c * NPC + q * 1024 + t];

    if (t < N_EXPERTS) run_base[t] = 0;
    __syncthreads();

#pragma unroll
    for (int q = 0; q < 4; ++q) {
        if (t < 16 * N_EXPERTS) ((int*)wave_cnt)[t] = 0;
        __syncthreads();

        // mask of lanes in this wave routed to the same expert
        uint64_t m = ~0ull;
#pragma unroll
        for (int b = 0; b < 5; ++b) {
            uint64_t bb = __ballot((e[q] >> b) & 1);
            m &= ((e[q] >> b) & 1) ? bb : ~bb;
        }
        const int rk = __popcll(m & ((1ull << lane) - 1ull));  // stable in-wave rank
        if (rk == 0) wave_cnt[w][e[q]] = __popcll(m);          // group leader
        __syncthreads();

        // cross-wave exclusive scan per expert, update running base
        if (t < N_EXPERTS) {
            int s = run_base[t];
#pragma unroll
            for (int ww = 0; ww < 16; ++ww) {
                wave_base[ww][t] = s;
                s += wave_cnt[ww][t];
            }
            run_base[t] = s;
        }
        __syncthreads();

        ws[WS_RANK + c * NPC + q * 1024 + t] = wave_base[w][e[q]] + rk;
        // next iteration's writes to wave_base occur only after two more
        // __syncthreads(), so the read above is safe without an extra barrier.
    }
    __syncthreads();
    if (t < N_EXPERTS) ws[WS_CNT + c * N_EXPERTS + t] = run_base[t];
}

// ---------------------------------------------------------------------------
// emit_kernel: 64 blocks x 256. Computes the cross-chip exclusive offsets
// (serialized chip order, as the reference), writes the inverse map and the
// per-expert totals (+ the experts_counter output).
// ---------------------------------------------------------------------------
__global__ __launch_bounds__(256) void emit_kernel(const int* __restrict__ idx,
                                                   int* __restrict__ ws,
                                                   float* __restrict__ out) {
    __shared__ int cnt_s[NUM_CHIPS * N_EXPERTS];
    const int t = threadIdx.x;
    if (t < NUM_CHIPS * N_EXPERTS) cnt_s[t] = ws[WS_CNT + t];
    __syncthreads();

    const int a = blockIdx.x * 256 + t;       // global assignment id, 0..16383
    const int c = a >> 12;                    // uniform within a block
    const int n = a & (NPC - 1);
    const int e = idx[a];

    int off = 0;
    for (int cc = 0; cc < c; ++cc) off += cnt_s[cc * N_EXPERTS + e];
    const int dst = off + ws[WS_RANK + a];
    ws[WS_INV + e * MAX_TOK + dst] = (c << 12) | n;

    if (blockIdx.x == 0 && t < N_EXPERTS) {
        int s = cnt_s[t] + cnt_s[N_EXPERTS + t] + cnt_s[2 * N_EXPERTS + t] +
                cnt_s[3 * N_EXPERTS + t];
        ws[WS_TOT + t] = s;
        out[CNT_OFF + t] = (float)s;
    }
}

// ---------------------------------------------------------------------------
// scatter_kernel: one block per output row. Occupancy test via slot < total[e]
// (no -1 init of inv needed). Copies the token's hidden vector (or zeros) and
// writes the 8-entry metadata row (or -1s).
// ---------------------------------------------------------------------------
__global__ __launch_bounds__(256) void scatter_kernel(const float* __restrict__ x,
                                                      const float* __restrict__ wts,
                                                      const int* __restrict__ ws,
                                                      float* __restrict__ out) {
    const int row = blockIdx.x;
    const int t = threadIdx.x;
    const int e = row >> 10;
    const int slot = row & (MAX_TOK - 1);

    float4* dst = (float4*)(out + (size_t)row * HIDDEN);

    if (slot < ws[WS_TOT + e]) {
        const int iv = ws[WS_INV + row];
        const int c = iv >> 12;
        const int n = iv & (NPC - 1);
        const int token = n >> 2;
        const float4* src = (const float4*)(x + ((size_t)c * SEQ + token) * HIDDEN);
#pragma unroll
        for (int i = 0; i < HIDDEN / 4 / 256; ++i)
            dst[t + i * 256] = src[t + i * 256];

        if (t < META_LEN) {
            float v = 0.0f;
            if (t == 0) v = (float)c;
            else if (t == 1) v = (float)token;
            else if (t == 2) v = (float)(n & 3);
            else if (t == 3) v = (float)e;
            else if (t == 4) {
                // bf16 bits of the routing weight, RNE (matches jax astype)
                float wv = wts[c * NPC + n];
                uint32_t ub;
                memcpy(&ub, &wv, 4);
                uint32_t lsb = (ub >> 16) & 1u;
                uint32_t bits = (ub + 0x7FFFu + lsb) >> 16;
                v = (float)(int)(short)(uint16_t)bits;  // sign-extend int16
            }
            out[META_OFF + (size_t)row * META_LEN + t] = v;
        }
    } else {
        const float4 z = make_float4(0.f, 0.f, 0.f, 0.f);
#pragma unroll
        for (int i = 0; i < HIDDEN / 4 / 256; ++i)
            dst[t + i * 256] = z;
        if (t < META_LEN)
            out[META_OFF + (size_t)row * META_LEN + t] = -1.0f;
    }
}

extern "C" void kernel_launch(void* const* d_in, const int* in_sizes, int n_in,
                              void* d_out, int out_size, void* d_ws, size_t ws_size,
                              hipStream_t stream) {
    const float* x   = (const float*)d_in[0];   // [4,1024,2048] f32
    const float* wts = (const float*)d_in[1];   // [4,1024,4]    f32
    const int*   idx = (const int*)d_in[2];     // [4,1024,4]    i32
    float* out = (float*)d_out;
    int* ws = (int*)d_ws;

    rank_kernel<<<NUM_CHIPS, 1024, 0, stream>>>(idx, ws);
    emit_kernel<<<NTOT / 256, 256, 0, stream>>>(idx, ws, out);
    scatter_kernel<<<ROWS, 256, 0, stream>>>(x, wts, ws, out);
}